// Round 2
// baseline (263.170 us; speedup 1.0000x reference)
//
#include <hip/hip_runtime.h>

// EquivariantProductBasisBlock (MACE symmetric contraction), fp32.
// B=2048, C=128, S=10, DIN=9, DOUTS=(1,3,5), PATHS=(1,3,8).
//
// R2: symmetrized per-(species,channel) tables.
//   out[b,c,m] = sum_{i<=j<=k} S3[m,t]*x_i*x_j*x_k + sum_{j<=k} S2[m,jk]*x_j*x_k
//              + sum_i S1[m,i]*x_i
// Table row per m: [S3 165 | S2 45 | S1 9 | pad] = 220 floats (8 KB LDS total).
// Each thread contracts TWO b's (table reads are wave-uniform broadcasts).
//
// mm slot -> (l, m): 0 -> (0,0); 1..3 -> (1, mm-1); 4..8 -> (2, mm-4)

#define NB 2048
#define NC 128
#define NS 10
#define ND 9      // DIN
#define NMM 9     // total m slots over l
#define ROWF 220  // floats per mm row (165+45+9+1 pad)

__host__ __device__ constexpr int pidx(int j, int k) {  // (j<=k) -> [0,45)
    return 9 * j - j * (j - 1) / 2 + (k - j);
}

struct TripTab {     // i<=j<=k triples in (i,j,k) ascending order, k fastest
    int ti[165], tj[165], tk[165], tp[165];
    constexpr TripTab() : ti{}, tj{}, tk{}, tp{} {
        int n = 0;
        for (int i = 0; i < 9; i++)
            for (int j = i; j < 9; j++)
                for (int k = j; k < 9; k++) {
                    ti[n] = i; tj[n] = j; tk[n] = k; tp[n] = pidx(j, k);
                    n++;
                }
    }
};
static constexpr TripTab TT{};

struct PairTab {     // j<=k pairs in pidx order
    int pj[45], pk[45];
    constexpr PairTab() : pj{}, pk{} {
        int n = 0;
        for (int j = 0; j < 9; j++)
            for (int k = j; k < 9; k++) { pj[n] = j; pk[n] = k; n++; }
    }
};
static constexpr PairTab PT{};

// ---------------- prep: deterministic counting sort of b by species ----------
__global__ __launch_bounds__(256) void prep_kernel(const float* __restrict__ attrs,
                                                   int* __restrict__ cnt,
                                                   int* __restrict__ start,
                                                   int* __restrict__ list)
{
    __shared__ int sc_[256][NS];    // inclusive scan over threads
    __shared__ int own_[256][NS];   // per-thread counts
    __shared__ int st_[NS];
    const int t = threadIdx.x;
    int myspec[8];
    #pragma unroll
    for (int e = 0; e < NS; e++) own_[t][e] = 0;
    #pragma unroll
    for (int r = 0; r < 8; r++) {
        const int b = t * 8 + r;
        const float* row = attrs + b * NS;
        int e = 0;
        #pragma unroll
        for (int s = 1; s < NS; s++) e = (row[s] > 0.5f) ? s : e;
        myspec[r] = e;
        own_[t][e] += 1;
    }
    #pragma unroll
    for (int e = 0; e < NS; e++) sc_[t][e] = own_[t][e];
    __syncthreads();
    for (int off = 1; off < 256; off <<= 1) {
        int tmp[NS];
        #pragma unroll
        for (int e = 0; e < NS; e++) tmp[e] = (t >= off) ? sc_[t - off][e] : 0;
        __syncthreads();
        #pragma unroll
        for (int e = 0; e < NS; e++) sc_[t][e] += tmp[e];
        __syncthreads();
    }
    if (t == 0) {
        int run = 0;
        for (int e = 0; e < NS; e++) {
            st_[e] = run; start[e] = run; cnt[e] = sc_[255][e]; run += sc_[255][e];
        }
    }
    __syncthreads();
    #pragma unroll
    for (int r = 0; r < 8; r++) {
        const int e = myspec[r];
        int rank = 0;
        #pragma unroll
        for (int r2 = 0; r2 < r; r2++) rank += (myspec[r2] == e) ? 1 : 0;
        const int pos = st_[e] + (sc_[t][e] - own_[t][e]) + rank;
        list[pos] = t * 8 + r;
    }
}

// ---------------- main: per-(e,c) symmetric table build + contraction --------
__global__ __launch_bounds__(128) void main_kernel(
    const float* __restrict__ x_in,
    const float* __restrict__ U1, const float* __restrict__ U2, const float* __restrict__ U3,
    const float* __restrict__ W1, const float* __restrict__ W2, const float* __restrict__ W3,
    const int* __restrict__ cnt, const int* __restrict__ start, const int* __restrict__ list,
    float* __restrict__ inter)
{
    const int c  = blockIdx.x;
    const int e  = blockIdx.y;
    const int ch = blockIdx.z;
    const int count = cnt[e];
    if (ch * 256 >= count) return;   // uniform early-exit (before any barrier)

    __shared__ float stab[NMM * ROWF];   // 7920 B
    __shared__ float w3s[3][8];
    __shared__ float w2s[3][3];
    __shared__ float w1s[3];

    const int t = threadIdx.x;
    if (t < 24)      { int l = t / 8, p = t % 8; w3s[l][p] = W3[((l * NS + e) * 8 + p) * NC + c]; }
    else if (t < 33) { int q = t - 24; int l = q / 3, p = q % 3; w2s[l][p] = W2[((l * NS + e) * 3 + p) * NC + c]; }
    else if (t < 36) { int l = t - 33; w1s[l] = W1[(l * NS + e) * NC + c]; }
    __syncthreads();

    // ---- build symmetrized table ----
    for (int n = t; n < NMM * ROWF; n += 128) {
        const int mm = n / ROWF;
        const int q  = n % ROWF;
        int l, m;
        if (mm == 0)     { l = 0; m = 0; }
        else if (mm < 4) { l = 1; m = mm - 1; }
        else             { l = 2; m = mm - 4; }
        const int lm = l * 5 + m;
        float val = 0.f;
        if (q < 165) {
            const int a = TT.ti[q], bb = TT.tj[q], cc = TT.tk[q];
            int P[6][3] = {{a,bb,cc},{a,cc,bb},{bb,a,cc},{bb,cc,a},{cc,a,bb},{cc,bb,a}};
            for (int u = 0; u < 6; u++) {
                bool dup = false;
                for (int r = 0; r < u; r++)
                    dup = dup || (P[r][0] == P[u][0] && P[r][1] == P[u][1] && P[r][2] == P[u][2]);
                if (dup) continue;
                const float4* u3q = (const float4*)(U3 + ((size_t)lm * 729 + P[u][0] * 81 + P[u][1] * 9 + P[u][2]) * 8);
                const float4 A = u3q[0], Bv = u3q[1];
                float av;
                av = A.x  * w3s[l][0];
                av = fmaf(A.y,  w3s[l][1], av);
                av = fmaf(A.z,  w3s[l][2], av);
                av = fmaf(A.w,  w3s[l][3], av);
                av = fmaf(Bv.x, w3s[l][4], av);
                av = fmaf(Bv.y, w3s[l][5], av);
                av = fmaf(Bv.z, w3s[l][6], av);
                av = fmaf(Bv.w, w3s[l][7], av);
                val += av;
            }
        } else if (q < 210) {
            const int n2 = q - 165;
            const int j = PT.pj[n2], k = PT.pk[n2];
            const float* u2a = U2 + ((size_t)lm * 81 + j * 9 + k) * 3;
            float av = fmaf(u2a[0], w2s[l][0], fmaf(u2a[1], w2s[l][1], u2a[2] * w2s[l][2]));
            if (j != k) {
                const float* u2b = U2 + ((size_t)lm * 81 + k * 9 + j) * 3;
                av += fmaf(u2b[0], w2s[l][0], fmaf(u2b[1], w2s[l][1], u2b[2] * w2s[l][2]));
            }
            val = av;
        } else if (q < 219) {
            val = U1[lm * 9 + (q - 210)] * w1s[l];
        }
        stab[n] = val;
    }
    __syncthreads();

    // ---- contraction: 2 b's per thread ----
    const int base = start[e] + ch * 256;
    const int idx0 = ch * 256 + t;
    const int idx1 = idx0 + 128;
    const bool act0 = idx0 < count;
    const bool act1 = idx1 < count;
    const int b0 = list[base + (act0 ? t : 0)];
    const int b1 = list[base + (act1 ? t + 128 : 0)];

    float xa[ND], xb[ND];
    const float* xpa = x_in + ((size_t)b0 * NC + c) * ND;
    const float* xpb = x_in + ((size_t)b1 * NC + c) * ND;
    #pragma unroll
    for (int k = 0; k < ND; k++) { xa[k] = xpa[k]; xb[k] = xpb[k]; }

    float m2a[45], m2b[45];
    #pragma unroll
    for (int j = 0; j < 9; j++)
        #pragma unroll
        for (int k = j; k < 9; k++) {
            m2a[pidx(j, k)] = xa[j] * xa[k];
            m2b[pidx(j, k)] = xb[j] * xb[k];
        }

    float* opa = inter + ((size_t)b0 * NC + c) * 12;
    float* opb = inter + ((size_t)b1 * NC + c) * 12;

    #pragma unroll 1
    for (int mm = 0; mm < NMM; mm++) {
        const float4* row4 = (const float4*)(stab + mm * ROWF);
        float a3a[9] = {0,0,0,0,0,0,0,0,0};
        float a3b[9] = {0,0,0,0,0,0,0,0,0};
        float La = 0.f, Lb = 0.f;
        auto proc = [&](int n, float v) {
            if (n < 165) {
                const int i = TT.ti[n], p = TT.tp[n];
                a3a[i] = fmaf(v, m2a[p], a3a[i]);
                a3b[i] = fmaf(v, m2b[p], a3b[i]);
            } else if (n < 210) {
                La = fmaf(v, m2a[n - 165], La);
                Lb = fmaf(v, m2b[n - 165], Lb);
            } else if (n < 219) {
                La = fmaf(v, xa[n - 210], La);
                Lb = fmaf(v, xb[n - 210], Lb);
            }
        };
        #pragma unroll
        for (int qq = 0; qq < 55; qq++) {
            const float4 v = row4[qq];
            proc(4 * qq + 0, v.x);
            proc(4 * qq + 1, v.y);
            proc(4 * qq + 2, v.z);
            proc(4 * qq + 3, v.w);
        }
        float ra = La, rb = Lb;
        #pragma unroll
        for (int i = 0; i < 9; i++) {
            ra = fmaf(xa[i], a3a[i], ra);
            rb = fmaf(xb[i], a3b[i], rb);
        }
        if (act0) opa[mm] = ra;
        if (act1) opb[mm] = rb;
    }
}

// ---------------- final: y[b,dd,m] = sum_c inter[b,c,mm]*Wlin[l,c,dd]/sqrt(C) + sc
__global__ __launch_bounds__(256) void final_kernel(
    const float* __restrict__ inter, const float* __restrict__ Wlin,
    const float* __restrict__ sc, float* __restrict__ out)
{
    __shared__ float sInter[4 * NC * 12];   // 24 KB
    const int t = threadIdx.x;
    const int b0 = blockIdx.x * 4;
    const float4* src = (const float4*)(inter + (size_t)b0 * NC * 12);
    float4* dst = (float4*)sInter;
    #pragma unroll
    for (int q = 0; q < 6; q++) dst[t + q * 256] = src[t + q * 256];
    __syncthreads();

    const int dd = t & 127;
    const int bh = t >> 7;
    float acc[2][NMM];
    #pragma unroll
    for (int u = 0; u < 2; u++)
        #pragma unroll
        for (int mm = 0; mm < NMM; mm++) acc[u][mm] = 0.f;

    const float* wp = Wlin + dd;
    for (int cc = 0; cc < NC; cc++) {
        float wl0 = wp[(0 * NC + cc) * NC];
        float wl1 = wp[(1 * NC + cc) * NC];
        float wl2 = wp[(2 * NC + cc) * NC];
        #pragma unroll
        for (int u = 0; u < 2; u++) {
            const float* ip = sInter + ((bh + u * 2) * NC + cc) * 12;
            float4 i0 = *(const float4*)ip;
            float4 i1 = *(const float4*)(ip + 4);
            float  i8 = ip[8];
            acc[u][0] = fmaf(i0.x, wl0, acc[u][0]);
            acc[u][1] = fmaf(i0.y, wl1, acc[u][1]);
            acc[u][2] = fmaf(i0.z, wl1, acc[u][2]);
            acc[u][3] = fmaf(i0.w, wl1, acc[u][3]);
            acc[u][4] = fmaf(i1.x, wl2, acc[u][4]);
            acc[u][5] = fmaf(i1.y, wl2, acc[u][5]);
            acc[u][6] = fmaf(i1.z, wl2, acc[u][6]);
            acc[u][7] = fmaf(i1.w, wl2, acc[u][7]);
            acc[u][8] = fmaf(i8,   wl2, acc[u][8]);
        }
    }

    const float inv = 0.08838834764831845f;   // 1/sqrt(128)
    #pragma unroll
    for (int u = 0; u < 2; u++) {
        const int b = b0 + bh + u * 2;
        float* orow = out + (size_t)b * 1152;
        const float* scrow = sc + (size_t)b * 1152;
        orow[dd] = fmaf(acc[u][0], inv, scrow[dd]);
        #pragma unroll
        for (int m = 0; m < 3; m++)
            orow[128 + dd * 3 + m] = fmaf(acc[u][1 + m], inv, scrow[128 + dd * 3 + m]);
        #pragma unroll
        for (int m = 0; m < 5; m++)
            orow[512 + dd * 5 + m] = fmaf(acc[u][4 + m], inv, scrow[512 + dd * 5 + m]);
    }
}

extern "C" void kernel_launch(void* const* d_in, const int* in_sizes, int n_in,
                              void* d_out, int out_size, void* d_ws, size_t ws_size,
                              hipStream_t stream) {
    const float* node_feats = (const float*)d_in[0];
    const float* node_attrs = (const float*)d_in[1];
    const float* sc   = (const float*)d_in[2];
    const float* U1   = (const float*)d_in[3];
    const float* U2   = (const float*)d_in[4];
    const float* U3   = (const float*)d_in[5];
    const float* W1   = (const float*)d_in[6];
    const float* W2   = (const float*)d_in[7];
    const float* W3   = (const float*)d_in[8];
    const float* Wlin = (const float*)d_in[9];
    float* out = (float*)d_out;

    char* ws = (char*)d_ws;
    int* cnt   = (int*)(ws + 0);
    int* start = (int*)(ws + 64);
    int* list  = (int*)(ws + 128);
    float* inter = (float*)(ws + 16384);   // NB*NC*12 floats = 12.58 MB

    hipLaunchKernelGGL(prep_kernel, dim3(1), dim3(256), 0, stream,
                       node_attrs, cnt, start, list);
    hipLaunchKernelGGL(main_kernel, dim3(NC, NS, 2), dim3(128), 0, stream,
                       node_feats, U1, U2, U3, W1, W2, W3, cnt, start, list, inter);
    hipLaunchKernelGGL(final_kernel, dim3(NB / 4), dim3(256), 0, stream,
                       inter, Wlin, sc, out);
}

// Round 3
// 252.690 us; speedup vs baseline: 1.0415x; 1.0415x over previous
//
#include <hip/hip_runtime.h>

// EquivariantProductBasisBlock (MACE symmetric contraction), fp32.
// B=2048, C=128, S=10, DIN=9, DOUTS=(1,3,5), PATHS=(1,3,8).
//
// R3: symmetrized table, row-major [t][mm] layout (t = monomial, mm = output).
//   Per (b,c):  out[mm] = sum_t S[t][mm] * mono_t(x),  t over
//   165 cubic (i<=j<=k) + 45 quadratic (j<=k) + 9 linear monomials.
//   9 independent accumulator chains -> ILP; 1 b per thread -> low VGPR.
// inter layout [c][slot] so main's stores are wave-coalesced; slot -> b via list.
//
// mm -> (l,m): 0 -> (0,0); 1..3 -> (1,mm-1); 4..8 -> (2,mm-4); lm = l*5+m.

#define NB 2048
#define NC 128
#define NS 10

__host__ __device__ constexpr int pidx(int j, int k) {  // (j<=k) -> [0,45)
    return 9 * j - j * (j - 1) / 2 + (k - j);
}
__host__ __device__ constexpr int tidx(int i, int j, int k) {  // (i<=j<=k) -> [0,165)
    int base = 0;
    for (int a = 0; a < i; a++) base += (9 - a) * (10 - a) / 2;
    const int d = 9 - i, jj = j - i;
    return base + d * jj - jj * (jj - 1) / 2 + (k - j);
}

struct TripTab {     // i<=j<=k in lexicographic order (matches tidx)
    int ti[165], tj[165], tk[165];
    constexpr TripTab() : ti{}, tj{}, tk{} {
        int n = 0;
        for (int i = 0; i < 9; i++)
            for (int j = i; j < 9; j++)
                for (int k = j; k < 9; k++) { ti[n] = i; tj[n] = j; tk[n] = k; n++; }
    }
};
static constexpr TripTab TT{};

struct PairTab {     // j<=k in pidx order
    int pj[45], pk[45];
    constexpr PairTab() : pj{}, pk{} {
        int n = 0;
        for (int j = 0; j < 9; j++)
            for (int k = j; k < 9; k++) { pj[n] = j; pk[n] = k; n++; }
    }
};
static constexpr PairTab PT{};

// ---------------- prep: deterministic counting sort of b by species ----------
__global__ __launch_bounds__(256) void prep_kernel(const float* __restrict__ attrs,
                                                   int* __restrict__ cnt,
                                                   int* __restrict__ start,
                                                   int* __restrict__ list)
{
    __shared__ int sc_[256][NS];
    __shared__ int own_[256][NS];
    __shared__ int st_[NS];
    const int t = threadIdx.x;
    int myspec[8];
    #pragma unroll
    for (int e = 0; e < NS; e++) own_[t][e] = 0;
    #pragma unroll
    for (int r = 0; r < 8; r++) {
        const int b = t * 8 + r;
        const float* row = attrs + b * NS;
        int e = 0;
        #pragma unroll
        for (int s = 1; s < NS; s++) e = (row[s] > 0.5f) ? s : e;
        myspec[r] = e;
        own_[t][e] += 1;
    }
    #pragma unroll
    for (int e = 0; e < NS; e++) sc_[t][e] = own_[t][e];
    __syncthreads();
    for (int off = 1; off < 256; off <<= 1) {
        int tmp[NS];
        #pragma unroll
        for (int e = 0; e < NS; e++) tmp[e] = (t >= off) ? sc_[t - off][e] : 0;
        __syncthreads();
        #pragma unroll
        for (int e = 0; e < NS; e++) sc_[t][e] += tmp[e];
        __syncthreads();
    }
    if (t == 0) {
        int run = 0;
        for (int e = 0; e < NS; e++) {
            st_[e] = run; start[e] = run; cnt[e] = sc_[255][e]; run += sc_[255][e];
        }
    }
    __syncthreads();
    #pragma unroll
    for (int r = 0; r < 8; r++) {
        const int e = myspec[r];
        int rank = 0;
        #pragma unroll
        for (int r2 = 0; r2 < r; r2++) rank += (myspec[r2] == e) ? 1 : 0;
        const int pos = st_[e] + (sc_[t][e] - own_[t][e]) + rank;
        list[pos] = t * 8 + r;
    }
}

// ---------------- main: per-(e,c) table build + per-b contraction ------------
__global__ __launch_bounds__(256) void main_kernel(
    const float* __restrict__ x_in,
    const float* __restrict__ U1, const float* __restrict__ U2, const float* __restrict__ U3,
    const float* __restrict__ W1, const float* __restrict__ W2, const float* __restrict__ W3,
    const int* __restrict__ cnt, const int* __restrict__ start, const int* __restrict__ list,
    float* __restrict__ inter)
{
    const int c = blockIdx.x;
    const int e = blockIdx.y;
    const int count = cnt[e];
    const int sbase = start[e];

    __shared__ float stab[219 * 12];   // 10512 B
    __shared__ float w3s[3][8];
    __shared__ float w2s[3][3];
    __shared__ float w1s[3];

    const int t = threadIdx.x;
    if (t < 24)      { int l = t / 8, p = t % 8; w3s[l][p] = W3[((l * NS + e) * 8 + p) * NC + c]; }
    else if (t < 33) { int q = t - 24; int l = q / 3, p = q % 3; w2s[l][p] = W2[((l * NS + e) * 3 + p) * NC + c]; }
    else if (t < 36) { int l = t - 33; w1s[l] = W1[(l * NS + e) * NC + c]; }
    __syncthreads();

    // ---- build symmetrized table: 1971 (row, mm) slots ----
    for (int n = t; n < 219 * 9; n += 256) {
        const int row = n / 9;
        const int mm = n - row * 9;
        int l, lm;
        if (mm == 0) { l = 0; lm = 0; } else if (mm < 4) { l = 1; lm = 4 + mm; } else { l = 2; lm = 6 + mm; }
        float val = 0.f;
        if (row < 165) {
            const int ia = TT.ti[row], jb = TT.tj[row], kc = TT.tk[row];
            const bool eab = (ia == jb), ebc = (jb == kc);
            const float* w = &w3s[l][0];
            float s = 0.f;
            auto addp = [&](int pi, int pj, int pk) {
                const float4* q = (const float4*)(U3 + ((size_t)lm * 729 + pi * 81 + pj * 9 + pk) * 8);
                const float4 A = q[0], Bv = q[1];
                float av = A.x * w[0];
                av = fmaf(A.y,  w[1], av);
                av = fmaf(A.z,  w[2], av);
                av = fmaf(A.w,  w[3], av);
                av = fmaf(Bv.x, w[4], av);
                av = fmaf(Bv.y, w[5], av);
                av = fmaf(Bv.z, w[6], av);
                av = fmaf(Bv.w, w[7], av);
                s += av;
            };
            addp(ia, jb, kc);
            if (!ebc)          addp(ia, kc, jb);
            if (!eab)          addp(jb, ia, kc);
            if (!eab)          addp(jb, kc, ia);
            if (!ebc)          addp(kc, ia, jb);
            if (!(eab || ebc)) addp(kc, jb, ia);
            val = s;
        } else if (row < 210) {
            const int n2 = row - 165;
            const int j = PT.pj[n2], k = PT.pk[n2];
            const float* u2a = U2 + ((size_t)lm * 81 + j * 9 + k) * 3;
            float av = fmaf(u2a[0], w2s[l][0], fmaf(u2a[1], w2s[l][1], u2a[2] * w2s[l][2]));
            if (j != k) {
                const float* u2b = U2 + ((size_t)lm * 81 + k * 9 + j) * 3;
                av = fmaf(u2b[0], w2s[l][0], fmaf(u2b[1], w2s[l][1], fmaf(u2b[2], w2s[l][2], av)));
            }
            val = av;
        } else {
            val = U1[lm * 9 + (row - 210)] * w1s[l];
        }
        stab[row * 12 + mm] = val;
    }
    __syncthreads();

    // ---- contraction: one (b,c) per thread, 9 independent acc chains ----
    for (int idx = t; idx < count; idx += 256) {
        const int slot = sbase + idx;
        const int b = list[slot];
        const float* xp = x_in + ((size_t)b * NC + c) * 9;
        float x[9];
        #pragma unroll
        for (int k = 0; k < 9; k++) x[k] = xp[k];

        float acc[9] = {0,0,0,0,0,0,0,0,0};

        #define ROWFMA(ROWIDX, MONO)                                          \
            {                                                                  \
                const float* r_ = stab + (ROWIDX) * 12;                        \
                const float4 r0_ = *(const float4*)r_;                         \
                const float4 r1_ = *(const float4*)(r_ + 4);                   \
                const float  r8_ = r_[8];                                      \
                const float  mo_ = (MONO);                                     \
                acc[0] = fmaf(r0_.x, mo_, acc[0]);                             \
                acc[1] = fmaf(r0_.y, mo_, acc[1]);                             \
                acc[2] = fmaf(r0_.z, mo_, acc[2]);                             \
                acc[3] = fmaf(r0_.w, mo_, acc[3]);                             \
                acc[4] = fmaf(r1_.x, mo_, acc[4]);                             \
                acc[5] = fmaf(r1_.y, mo_, acc[5]);                             \
                acc[6] = fmaf(r1_.z, mo_, acc[6]);                             \
                acc[7] = fmaf(r1_.w, mo_, acc[7]);                             \
                acc[8] = fmaf(r8_,  mo_, acc[8]);                              \
            }

        #pragma unroll
        for (int i = 0; i < 9; i++) {
            #pragma unroll
            for (int j = i; j < 9; j++) {
                const float xij = x[i] * x[j];
                #pragma unroll
                for (int k = j; k < 9; k++) {
                    ROWFMA(tidx(i, j, k), xij * x[k]);
                }
            }
        }
        #pragma unroll
        for (int j = 0; j < 9; j++) {
            #pragma unroll
            for (int k = j; k < 9; k++) {
                ROWFMA(165 + pidx(j, k), x[j] * x[k]);
            }
        }
        #pragma unroll
        for (int i = 0; i < 9; i++) {
            ROWFMA(210 + i, x[i]);
        }
        #undef ROWFMA

        float* op = inter + ((size_t)c * NB + slot) * 12;
        *(float4*)(op)     = make_float4(acc[0], acc[1], acc[2], acc[3]);
        *(float4*)(op + 4) = make_float4(acc[4], acc[5], acc[6], acc[7]);
        *(float4*)(op + 8) = make_float4(acc[8], 0.f, 0.f, 0.f);
    }
}

// ---------------- final: y[b,dd,m] = sum_c inter[c,slot,mm]*Wlin[l,c,dd]/sqrt(C) + sc
__global__ __launch_bounds__(256) void final_kernel(
    const float* __restrict__ inter, const float* __restrict__ Wlin,
    const float* __restrict__ sc, const int* __restrict__ list,
    float* __restrict__ out)
{
    __shared__ float sInter[4 * NC * 12];   // 24 KB, layout [s][c][12]
    const int t = threadIdx.x;
    const int s0 = blockIdx.x * 4;
    #pragma unroll
    for (int q = 0; q < 6; q++) {
        const int flat = t + q * 256;        // [0, 1536)
        const int q3 = flat % 3;
        const int cs = flat / 3;             // [0, 512)
        const int cc = cs >> 2, s = cs & 3;
        const float4 v = *(const float4*)(inter + ((size_t)cc * NB + s0 + s) * 12 + q3 * 4);
        *(float4*)(&sInter[(s * NC + cc) * 12 + q3 * 4]) = v;
    }
    __syncthreads();

    const int dd = t & 127;
    const int bh = t >> 7;
    float acc[2][9];
    #pragma unroll
    for (int u = 0; u < 2; u++)
        #pragma unroll
        for (int mm = 0; mm < 9; mm++) acc[u][mm] = 0.f;

    const float* wp = Wlin + dd;
    for (int cc = 0; cc < NC; cc++) {
        const float wl0 = wp[(0 * NC + cc) * NC];
        const float wl1 = wp[(1 * NC + cc) * NC];
        const float wl2 = wp[(2 * NC + cc) * NC];
        #pragma unroll
        for (int u = 0; u < 2; u++) {
            const float* ip = sInter + ((bh + u * 2) * NC + cc) * 12;
            const float4 i0 = *(const float4*)ip;
            const float4 i1 = *(const float4*)(ip + 4);
            const float  i8 = ip[8];
            acc[u][0] = fmaf(i0.x, wl0, acc[u][0]);
            acc[u][1] = fmaf(i0.y, wl1, acc[u][1]);
            acc[u][2] = fmaf(i0.z, wl1, acc[u][2]);
            acc[u][3] = fmaf(i0.w, wl1, acc[u][3]);
            acc[u][4] = fmaf(i1.x, wl2, acc[u][4]);
            acc[u][5] = fmaf(i1.y, wl2, acc[u][5]);
            acc[u][6] = fmaf(i1.z, wl2, acc[u][6]);
            acc[u][7] = fmaf(i1.w, wl2, acc[u][7]);
            acc[u][8] = fmaf(i8,   wl2, acc[u][8]);
        }
    }

    const float inv = 0.08838834764831845f;   // 1/sqrt(128)
    #pragma unroll
    for (int u = 0; u < 2; u++) {
        const int s = s0 + bh + u * 2;
        const int b = list[s];
        float* orow = out + (size_t)b * 1152;
        const float* scrow = sc + (size_t)b * 1152;
        orow[dd] = fmaf(acc[u][0], inv, scrow[dd]);
        #pragma unroll
        for (int m = 0; m < 3; m++)
            orow[128 + dd * 3 + m] = fmaf(acc[u][1 + m], inv, scrow[128 + dd * 3 + m]);
        #pragma unroll
        for (int m = 0; m < 5; m++)
            orow[512 + dd * 5 + m] = fmaf(acc[u][4 + m], inv, scrow[512 + dd * 5 + m]);
    }
}

extern "C" void kernel_launch(void* const* d_in, const int* in_sizes, int n_in,
                              void* d_out, int out_size, void* d_ws, size_t ws_size,
                              hipStream_t stream) {
    const float* node_feats = (const float*)d_in[0];
    const float* node_attrs = (const float*)d_in[1];
    const float* sc   = (const float*)d_in[2];
    const float* U1   = (const float*)d_in[3];
    const float* U2   = (const float*)d_in[4];
    const float* U3   = (const float*)d_in[5];
    const float* W1   = (const float*)d_in[6];
    const float* W2   = (const float*)d_in[7];
    const float* W3   = (const float*)d_in[8];
    const float* Wlin = (const float*)d_in[9];
    float* out = (float*)d_out;

    char* ws = (char*)d_ws;
    int* cnt   = (int*)(ws + 0);
    int* start = (int*)(ws + 64);
    int* list  = (int*)(ws + 128);
    float* inter = (float*)(ws + 16384);   // NC*NB*12 floats = 12.58 MB

    hipLaunchKernelGGL(prep_kernel, dim3(1), dim3(256), 0, stream,
                       node_attrs, cnt, start, list);
    hipLaunchKernelGGL(main_kernel, dim3(NC, NS), dim3(256), 0, stream,
                       node_feats, U1, U2, U3, W1, W2, W3, cnt, start, list, inter);
    hipLaunchKernelGGL(final_kernel, dim3(NB / 4), dim3(256), 0, stream,
                       inter, Wlin, sc, list, out);
}